// Round 11
// baseline (137.782 us; speedup 1.0000x reference)
//
#include <hip/hip_runtime.h>
#include <hip/hip_bf16.h>

typedef __attribute__((ext_vector_type(8))) short s16x8;
typedef __attribute__((ext_vector_type(4))) float f32x4;

__device__ __forceinline__ ushort f2bf(float f) {
  union { float f; unsigned int u; } c; c.f = f;
  unsigned int u = c.u + 0x7fffu + ((c.u >> 16) & 1u);
  return (ushort)(u >> 16);
}

__device__ __forceinline__ unsigned int pack2(float lo, float hi) {
  __hip_bfloat162 b2 = __float22bfloat162_rn(make_float2(lo, hi));
  union { __hip_bfloat162 b; unsigned int u; } c; c.b = b2;
  return c.u;
}

__device__ __forceinline__ s16x8 ld16(const ushort* p) {
  union { uint4 u; s16x8 s; } c;
  c.u = *reinterpret_cast<const uint4*>(p);
  return c.s;
}

__device__ __forceinline__ f32x4 mfma16(s16x8 a, s16x8 b, f32x4 c) {
  return __builtin_amdgcn_mfma_f32_16x16x32_bf16(a, b, c, 0, 0, 0);
}

__device__ __forceinline__ float exp2fast(float x) { return __builtin_amdgcn_exp2f(x); }

__device__ __forceinline__ void gld_lds16(const void* g, void* l) {
  __builtin_amdgcn_global_load_lds(
      (const __attribute__((address_space(1))) void*)g,
      (__attribute__((address_space(3))) void*)l, 16, 0, 0);
}

// ---------------- prep: x cast + 3 weight transpose-casts, one kernel ----------------

__global__ __launch_bounds__(256) void k_prep(
    const float* __restrict__ x, ushort* __restrict__ xb,
    const float* __restrict__ Wr, ushort* __restrict__ WtR,
    const float* __restrict__ Wd, ushort* __restrict__ WtD,
    const float* __restrict__ Wp, ushort* __restrict__ WtP) {
  __shared__ float tile[32][33];
  int b = blockIdx.x, t = threadIdx.x;
  if (b < 8192) {
    int i = (b * 256 + t) * 4;
    float4 v = *reinterpret_cast<const float4*>(x + i);
    ushort4 o;
    o.x = f2bf(v.x); o.y = f2bf(v.y); o.z = f2bf(v.z); o.w = f2bf(v.w);
    *reinterpret_cast<ushort4*>(xb + i) = o;
    return;
  }
  b -= 8192;
  const float* src; ushort* dst; int N;
  if (b < 768)      { src = Wr; dst = WtR; N = 1536; }
  else if (b < 1536){ b -= 768;  src = Wd; dst = WtD; N = 1536; }
  else              { b -= 1536; src = Wp; dst = WtP; N = 512; }
  int nb = N >> 5;
  int n0 = (b % nb) * 32, k0 = (b / nb) * 32;
  int tx = t & 31, ty = t >> 5;
#pragma unroll
  for (int i = 0; i < 32; i += 8)
    tile[ty + i][tx] = src[(k0 + ty + i) * N + (n0 + tx)];
  __syncthreads();
#pragma unroll
  for (int i = 0; i < 32; i += 8)
    dst[(size_t)(n0 + ty + i) * 512 + (k0 + tx)] = f2bf(tile[tx][ty + i]);
}

// ---------------- GEMM helpers ----------------

__device__ __forceinline__ void stage_lds(const ushort* __restrict__ src, int ld,
                                          char* ldsbase, int t) {
#pragma unroll
  for (int p = 0; p < 4; ++p) {
    int chunk = p * 256 + t;
    int r = chunk >> 3, cc = chunk & 7;
    gld_lds16(src + r * ld + ((cc ^ (r & 7)) * 8), ldsbase + (chunk & ~63) * 16);
  }
}

__device__ __forceinline__ s16x8 lds_frag(const char* lds, int row, int c) {
  union { uint4 u; s16x8 s; } cv;
  cv.u = *reinterpret_cast<const uint4*>(lds + row * 128 + ((c ^ (row & 7)) * 16));
  return cv.s;
}

// ---------------- QKV GEMM (templated, 2-phase double-buffered staging) ----------------

template <bool TRANS>
__global__ __launch_bounds__(256) void k_qkv(
    const ushort* __restrict__ xb, const ushort* __restrict__ WtR,
    const ushort* __restrict__ WtD, const float* __restrict__ bR,
    const float* __restrict__ bD, ushort* __restrict__ Qb,
    ushort* __restrict__ Kb, ushort* __restrict__ Vt) {
  __shared__ __align__(16) char lds[65536];
  int m0 = blockIdx.x * 128;
  int n0 = (TRANS ? 1024 : 0) + blockIdx.y * 128;
  int s = m0 >> 13, bb = (m0 >> 10) & 7, lbase = m0 & 1023;
  const ushort* A = xb + (size_t)(bb * 2048 + s * 1024 + lbase) * 512;
  const ushort* Wt = (s ? WtD : WtR) + (size_t)n0 * 512;
  const float* bias = s ? bD : bR;
  int t = threadIdx.x;
  int wid = t >> 6, ln = t & 15, g = (t & 63) >> 4;
  int wr = wid >> 1, wc = wid & 1;
  f32x4 acc[4][4] = {};
  stage_lds(A, 512, lds, t);
  stage_lds(Wt, 512, lds + 16384, t);
  __syncthreads();
  for (int ks = 0; ks < 8; ++ks) {
    char* cbuf = lds + (ks & 1) * 32768;
    if (ks < 7) {
      char* nbuf = lds + ((ks + 1) & 1) * 32768;
      stage_lds(A + (ks + 1) * 64, 512, nbuf, t);
      stage_lds(Wt + (ks + 1) * 64, 512, nbuf + 16384, t);
    }
    char* ldsA = cbuf;
    char* ldsB = cbuf + 16384;
#pragma unroll
    for (int kk = 0; kk < 2; ++kk) {
      s16x8 af[4], bf[4];
#pragma unroll
      for (int mi = 0; mi < 4; ++mi) af[mi] = lds_frag(ldsA, wr * 64 + mi * 16 + ln, kk * 4 + g);
#pragma unroll
      for (int ni = 0; ni < 4; ++ni) bf[ni] = lds_frag(ldsB, wc * 64 + ni * 16 + ln, kk * 4 + g);
#pragma unroll
      for (int mi = 0; mi < 4; ++mi)
#pragma unroll
        for (int ni = 0; ni < 4; ++ni)
          acc[mi][ni] = TRANS ? mfma16(bf[ni], af[mi], acc[mi][ni])
                              : mfma16(af[mi], bf[ni], acc[mi][ni]);
    }
    __syncthreads();
  }
  int hb_base = (s * 8 + bb) * 8;
  if (!TRANS) {
    bool isK = (n0 >> 9) != 0;
    ushort* dst = isK ? Kb : Qb;
    float sc = isK ? 1.0f : 0.18033688011112042f;  // 0.125 * log2(e)
#pragma unroll
    for (int mi = 0; mi < 4; ++mi)
#pragma unroll
      for (int ni = 0; ni < 4; ++ni) {
        f32x4 v = acc[mi][ni];
        int col = n0 + wc * 64 + ni * 16 + ln;
        int h = (col >> 6) & 7, d = col & 63;
        float bv = bias[col];
        ushort* hp = dst + ((size_t)(hb_base + h) << 16);
        int lr = lbase + wr * 64 + mi * 16 + g * 4;
#pragma unroll
        for (int j = 0; j < 4; ++j) hp[(lr + j) * 64 + d] = f2bf((v[j] + bv) * sc);
      }
  } else {
    // epilogue via LDS (staging buffers free after final sync):
    // tile [128 c-rows][128 phi(l) cols], 16B-chunk XOR swizzle, then coalesced stores.
    ushort* et = (ushort*)lds;
#pragma unroll
    for (int mi = 0; mi < 4; ++mi) {
      int ll = wr * 64 + mi * 16 + ln;
      int lpl = (ll & ~63) | (ll & 0x23) | ((ll & 0x0C) << 1) | ((ll & 0x10) >> 2);
      int chunk = lpl >> 3, within = lpl & 7;
#pragma unroll
      for (int ni = 0; ni < 4; ++ni) {
        f32x4 v = acc[mi][ni];
        int crb = wc * 64 + ni * 16 + g * 4;
#pragma unroll
        for (int j = 0; j < 4; ++j) {
          int cr = crb + j;
          float bv = bias[n0 + cr];
          *(ushort*)((char*)et + cr * 256 + ((chunk ^ (cr & 15)) * 16) + within * 2)
              = f2bf(v[j] + bv);
        }
      }
    }
    __syncthreads();
#pragma unroll
    for (int pass = 0; pass < 8; ++pass) {
      int rrow = pass * 16 + (t >> 4);
      int c16 = t & 15;
      int col = n0 + rrow;
      int h = (col >> 6) & 7, d = col & 63;
      uint4 vv = *(const uint4*)((const char*)et + rrow * 256 + ((c16 ^ (rrow & 15)) * 16));
      *reinterpret_cast<uint4*>(Vt + ((size_t)(hb_base + h) << 16) + d * 1024 + lbase + c16 * 8)
          = vv;
    }
  }
}

// ---------------- attention (512 thr, 8 waves x 32q, 3-deep 48KB, counted vmcnt) --------
// Per thread 2 stage ops/tile (1 K + 1 V). Prologue: stage(0),stage(1); vmcnt(2); barrier.
// Iter t: issue stage(t+2) into bs; compute(t) from bc; vmcnt(2) completes stage(t+1),
// leaves stage(t+2) in flight across the barrier (never drains in steady state).
// Buffer safety: stage(t+2) overwrites buf[(t-1)%3], whose readers all passed the
// end-of-(t-1) barrier. Tail waits: vmcnt(2)/vmcnt(0)/none at t<=13 / t==14 / t==15.

__global__ __launch_bounds__(512) void k_attn(const ushort* __restrict__ Qb,
                                              const ushort* __restrict__ Kb,
                                              const ushort* __restrict__ Vt,
                                              ushort* __restrict__ AO) {
  __shared__ __align__(16) char lds[49152];   // 3 x (K 8KB + V 8KB)
  int bid = blockIdx.x;
  int set = bid & 127, qb = bid >> 7;          // qb in 0..3, 256 q-rows per block
  int pair = set & 1, h = (set >> 1) & 7, bb = set >> 4;
  int sQ = 1 - pair, sKV = pair;
  const ushort* Qp = Qb + ((size_t)((sQ * 8 + bb) * 8 + h) << 16);
  const ushort* Kp = Kb + ((size_t)((sKV * 8 + bb) * 8 + h) << 16);
  const ushort* Vp = Vt + ((size_t)((sKV * 8 + bb) * 8 + h) << 16);
  int t = threadIdx.x, w = t >> 6, ln = t & 15, g = (t & 63) >> 4;
  int q0 = qb * 256 + w * 32;
  s16x8 qf0a = ld16(Qp + (q0 + ln) * 64 + g * 8);
  s16x8 qf1a = ld16(Qp + (q0 + ln) * 64 + 32 + g * 8);
  s16x8 qf0b = ld16(Qp + (q0 + 16 + ln) * 64 + g * 8);
  s16x8 qf1b = ld16(Qp + (q0 + 16 + ln) * 64 + 32 + g * 8);

  int r = t >> 3, cc = t & 7;
  int kof = r * 64 + ((cc ^ (r & 7)) * 8);
  int vof = r * 1024 + ((cc ^ (r & 7)) * 8);
  int ldst = (t & ~63) * 16;

  float ls_a = 0.f, ls_b = 0.f;
  f32x4 oca[4] = {}, ocb[4] = {};

  const ushort* kstage = Kp;   // +4096 per staged K tile
  const ushort* vstage = Vp;   // +64 per staged V tile

  char* bc = lds;
  char* bn = lds + 16384;
  char* bs = lds + 32768;

  // prologue: tile0 -> bc, tile1 -> bn
  gld_lds16(kstage + kof, bc + ldst);
  gld_lds16(vstage + vof, bc + 8192 + ldst);
  kstage += 4096; vstage += 64;
  gld_lds16(kstage + kof, bn + ldst);
  gld_lds16(vstage + vof, bn + 8192 + ldst);
  kstage += 4096; vstage += 64;
  asm volatile("s_waitcnt vmcnt(2)" ::: "memory");
  __builtin_amdgcn_sched_barrier(0);
  __builtin_amdgcn_s_barrier();
  __builtin_amdgcn_sched_barrier(0);

  for (int it = 0; it < 16; ++it) {
    if (it < 14) {
      gld_lds16(kstage + kof, bs + ldst);
      gld_lds16(vstage + vof, bs + 8192 + ldst);
      kstage += 4096; vstage += 64;
    }

    f32x4 za[4], zb[4];
    __builtin_amdgcn_s_setprio(1);
#pragma unroll
    for (int s = 0; s < 4; ++s) {
      s16x8 k0 = lds_frag(bc, s * 16 + ln, g);
      s16x8 k1 = lds_frag(bc, s * 16 + ln, 4 + g);
      f32x4 z1 = {}; z1 = mfma16(k0, qf0a, z1); z1 = mfma16(k1, qf1a, z1); za[s] = z1;
      f32x4 z2 = {}; z2 = mfma16(k0, qf0b, z2); z2 = mfma16(k1, qf1b, z2); zb[s] = z2;
    }
    __builtin_amdgcn_s_setprio(0);

    unsigned int pwa[8], pwb[8];
#pragma unroll
    for (int s = 0; s < 4; ++s) {
      float p0 = exp2fast(za[s][0]), p1 = exp2fast(za[s][1]);
      float p2 = exp2fast(za[s][2]), p3 = exp2fast(za[s][3]);
      ls_a += (p0 + p1) + (p2 + p3);
      pwa[2 * s] = pack2(p0, p1); pwa[2 * s + 1] = pack2(p2, p3);
      float r0 = exp2fast(zb[s][0]), r1 = exp2fast(zb[s][1]);
      float r2 = exp2fast(zb[s][2]), r3 = exp2fast(zb[s][3]);
      ls_b += (r0 + r1) + (r2 + r3);
      pwb[2 * s] = pack2(r0, r1); pwb[2 * s + 1] = pack2(r2, r3);
    }
    union { uint4 u; s16x8 v; } c0, c1, c2, c3;
    c0.u = make_uint4(pwa[0], pwa[1], pwa[2], pwa[3]);
    c1.u = make_uint4(pwa[4], pwa[5], pwa[6], pwa[7]);
    c2.u = make_uint4(pwb[0], pwb[1], pwb[2], pwb[3]);
    c3.u = make_uint4(pwb[4], pwb[5], pwb[6], pwb[7]);
    s16x8 pf0a = c0.v, pf1a = c1.v, pf0b = c2.v, pf1b = c3.v;

    __builtin_amdgcn_s_setprio(1);
#pragma unroll
    for (int d = 0; d < 4; ++d) {
      s16x8 v0 = lds_frag(bc + 8192, d * 16 + ln, g);
      s16x8 v1 = lds_frag(bc + 8192, d * 16 + ln, 4 + g);
      oca[d] = mfma16(v0, pf0a, oca[d]);
      oca[d] = mfma16(v1, pf1a, oca[d]);
      ocb[d] = mfma16(v0, pf0b, ocb[d]);
      ocb[d] = mfma16(v1, pf1b, ocb[d]);
    }
    __builtin_amdgcn_s_setprio(0);

    if (it < 15) {
      if (it < 14) {
        asm volatile("s_waitcnt vmcnt(2)" ::: "memory");
      } else {
        asm volatile("s_waitcnt vmcnt(0)" ::: "memory");
      }
      __builtin_amdgcn_sched_barrier(0);
      __builtin_amdgcn_s_barrier();
      __builtin_amdgcn_sched_barrier(0);
    }
    char* tmp = bc; bc = bn; bn = bs; bs = tmp;
  }

  ls_a += __shfl_xor(ls_a, 16, 64);
  ls_a += __shfl_xor(ls_a, 32, 64);
  ls_b += __shfl_xor(ls_b, 16, 64);
  ls_b += __shfl_xor(ls_b, 32, 64);
  float inva = 1.0f / ls_a, invb = 1.0f / ls_b;
  int orow = bb * 2048 + pair * 1024 + q0 + ln;
#pragma unroll
  for (int d = 0; d < 4; ++d) {
    uint2 st;
    st.x = pack2(oca[d][0] * inva, oca[d][1] * inva);
    st.y = pack2(oca[d][2] * inva, oca[d][3] * inva);
    *reinterpret_cast<uint2*>(AO + (size_t)orow * 512 + h * 64 + d * 16 + 4 * g) = st;
    uint2 st2;
    st2.x = pack2(ocb[d][0] * invb, ocb[d][1] * invb);
    st2.y = pack2(ocb[d][2] * invb, ocb[d][3] * invb);
    *reinterpret_cast<uint2*>(AO + (size_t)(orow + 16) * 512 + h * 64 + d * 16 + 4 * g) = st2;
  }
}

// ---------------- output projection GEMM (2-phase double-buffered) ----------------

__global__ __launch_bounds__(256) void k_gemm_proj(const ushort* __restrict__ AO,
                                                   const ushort* __restrict__ WtP,
                                                   const float* __restrict__ bP,
                                                   float* __restrict__ Out) {
  __shared__ __align__(16) char lds[65536];
  int m0 = blockIdx.x * 128, n0 = blockIdx.y * 128;
  const ushort* A = AO + (size_t)m0 * 512;
  const ushort* Wt = WtP + (size_t)n0 * 512;
  int t = threadIdx.x;
  int wid = t >> 6, ln = t & 15, g = (t & 63) >> 4;
  int wr = wid >> 1, wc = wid & 1;
  f32x4 acc[4][4] = {};
  stage_lds(A, 512, lds, t);
  stage_lds(Wt, 512, lds + 16384, t);
  __syncthreads();
  for (int ks = 0; ks < 8; ++ks) {
    char* cbuf = lds + (ks & 1) * 32768;
    if (ks < 7) {
      char* nbuf = lds + ((ks + 1) & 1) * 32768;
      stage_lds(A + (ks + 1) * 64, 512, nbuf, t);
      stage_lds(Wt + (ks + 1) * 64, 512, nbuf + 16384, t);
    }
    char* ldsA = cbuf;
    char* ldsB = cbuf + 16384;
#pragma unroll
    for (int kk = 0; kk < 2; ++kk) {
      s16x8 af[4], bf[4];
#pragma unroll
      for (int mi = 0; mi < 4; ++mi) af[mi] = lds_frag(ldsA, wr * 64 + mi * 16 + ln, kk * 4 + g);
#pragma unroll
      for (int ni = 0; ni < 4; ++ni) bf[ni] = lds_frag(ldsB, wc * 64 + ni * 16 + ln, kk * 4 + g);
#pragma unroll
      for (int mi = 0; mi < 4; ++mi)
#pragma unroll
        for (int ni = 0; ni < 4; ++ni) acc[mi][ni] = mfma16(af[mi], bf[ni], acc[mi][ni]);
    }
    __syncthreads();
  }
#pragma unroll
  for (int mi = 0; mi < 4; ++mi)
#pragma unroll
    for (int ni = 0; ni < 4; ++ni) {
      f32x4 v = acc[mi][ni];
      int col = n0 + wc * 64 + ni * 16 + ln;
      float bv = bP[col];
      int r0 = m0 + wr * 64 + mi * 16 + g * 4;
#pragma unroll
      for (int j = 0; j < 4; ++j) Out[(size_t)(r0 + j) * 512 + col] = v[j] + bv;
    }
}

// ---------------- launch ----------------

extern "C" void kernel_launch(void* const* d_in, const int* in_sizes, int n_in,
                              void* d_out, int out_size, void* d_ws, size_t ws_size,
                              hipStream_t stream) {
  const float* x      = (const float*)d_in[0];
  const float* W_rgb  = (const float*)d_in[1];
  const float* b_rgb  = (const float*)d_in[2];
  const float* W_dep  = (const float*)d_in[3];
  const float* b_dep  = (const float*)d_in[4];
  const float* W_proj = (const float*)d_in[5];
  const float* b_proj = (const float*)d_in[6];
  float* out = (float*)d_out;

  char* ws = (char*)d_ws;
  ushort* xb  = (ushort*)(ws + 0);
  ushort* WtR = (ushort*)(ws + 16777216);
  ushort* WtD = (ushort*)(ws + 18350080);
  ushort* WtP = (ushort*)(ws + 19922944);
  ushort* Qb  = (ushort*)(ws + 20447232);
  ushort* Kb  = (ushort*)(ws + 37224448);
  ushort* Vt  = (ushort*)(ws + 54001664);
  ushort* AO  = (ushort*)(ws + 70778880);

  k_prep<<<9984, 256, 0, stream>>>(x, xb, W_rgb, WtR, W_dep, WtD, W_proj, WtP);
  k_qkv<false><<<dim3(128, 8), 256, 0, stream>>>(xb, WtR, WtD, b_rgb, b_dep, Qb, Kb, Vt);
  k_qkv<true><<<dim3(128, 4), 256, 0, stream>>>(xb, WtR, WtD, b_rgb, b_dep, Qb, Kb, Vt);
  k_attn<<<512, 512, 0, stream>>>(Qb, Kb, Vt, AO);
  k_gemm_proj<<<dim3(128, 4), 256, 0, stream>>>(AO, WtP, b_proj, out);
}

// Round 12
// 131.594 us; speedup vs baseline: 1.0470x; 1.0470x over previous
//
#include <hip/hip_runtime.h>
#include <hip/hip_bf16.h>

typedef __attribute__((ext_vector_type(8))) short s16x8;
typedef __attribute__((ext_vector_type(4))) float f32x4;

__device__ __forceinline__ ushort f2bf(float f) {
  union { float f; unsigned int u; } c; c.f = f;
  unsigned int u = c.u + 0x7fffu + ((c.u >> 16) & 1u);
  return (ushort)(u >> 16);
}

__device__ __forceinline__ unsigned int pack2(float lo, float hi) {
  __hip_bfloat162 b2 = __float22bfloat162_rn(make_float2(lo, hi));
  union { __hip_bfloat162 b; unsigned int u; } c; c.b = b2;
  return c.u;
}

__device__ __forceinline__ s16x8 ld16(const ushort* p) {
  union { uint4 u; s16x8 s; } c;
  c.u = *reinterpret_cast<const uint4*>(p);
  return c.s;
}

__device__ __forceinline__ f32x4 mfma16(s16x8 a, s16x8 b, f32x4 c) {
  return __builtin_amdgcn_mfma_f32_16x16x32_bf16(a, b, c, 0, 0, 0);
}

__device__ __forceinline__ float exp2fast(float x) { return __builtin_amdgcn_exp2f(x); }

__device__ __forceinline__ void gld_lds16(const void* g, void* l) {
  __builtin_amdgcn_global_load_lds(
      (const __attribute__((address_space(1))) void*)g,
      (__attribute__((address_space(3))) void*)l, 16, 0, 0);
}

// ---------------- prep: x cast + 3 weight transpose-casts, one kernel ----------------

__global__ __launch_bounds__(256) void k_prep(
    const float* __restrict__ x, ushort* __restrict__ xb,
    const float* __restrict__ Wr, ushort* __restrict__ WtR,
    const float* __restrict__ Wd, ushort* __restrict__ WtD,
    const float* __restrict__ Wp, ushort* __restrict__ WtP) {
  __shared__ float tile[32][33];
  int b = blockIdx.x, t = threadIdx.x;
  if (b < 8192) {
    int i = (b * 256 + t) * 4;
    float4 v = *reinterpret_cast<const float4*>(x + i);
    ushort4 o;
    o.x = f2bf(v.x); o.y = f2bf(v.y); o.z = f2bf(v.z); o.w = f2bf(v.w);
    *reinterpret_cast<ushort4*>(xb + i) = o;
    return;
  }
  b -= 8192;
  const float* src; ushort* dst; int N;
  if (b < 768)      { src = Wr; dst = WtR; N = 1536; }
  else if (b < 1536){ b -= 768;  src = Wd; dst = WtD; N = 1536; }
  else              { b -= 1536; src = Wp; dst = WtP; N = 512; }
  int nb = N >> 5;
  int n0 = (b % nb) * 32, k0 = (b / nb) * 32;
  int tx = t & 31, ty = t >> 5;
#pragma unroll
  for (int i = 0; i < 32; i += 8)
    tile[ty + i][tx] = src[(k0 + ty + i) * N + (n0 + tx)];
  __syncthreads();
#pragma unroll
  for (int i = 0; i < 32; i += 8)
    dst[(size_t)(n0 + ty + i) * 512 + (k0 + tx)] = f2bf(tile[tx][ty + i]);
}

// ---------------- helpers ----------------

// 128x64 tile frag read (8-chunk rows, swizzle by row&7)  -- used by attn & proj
__device__ __forceinline__ s16x8 lds_frag(const char* lds, int row, int c) {
  union { uint4 u; s16x8 s; } cv;
  cv.u = *reinterpret_cast<const uint4*>(lds + row * 128 + ((c ^ (row & 7)) * 16));
  return cv.s;
}

// 128x32 tile frag read (4-chunk rows, swizzle by (row>>1)&3) -- used by qkv
__device__ __forceinline__ s16x8 lds_frag32(const char* lds, int row, int c) {
  union { uint4 u; s16x8 s; } cv;
  cv.u = *reinterpret_cast<const uint4*>(lds + row * 64 + ((c ^ ((row >> 1) & 3)) * 16));
  return cv.s;
}

__device__ __forceinline__ void stage_lds(const ushort* __restrict__ src, int ld,
                                          char* ldsbase, int t) {
#pragma unroll
  for (int p = 0; p < 4; ++p) {
    int chunk = p * 256 + t;
    int r = chunk >> 3, cc = chunk & 7;
    gld_lds16(src + r * ld + ((cc ^ (r & 7)) * 8), ldsbase + (chunk & ~63) * 16);
  }
}

// ---------------- QKV GEMM: BK=32, 3-deep counted pipeline, 48KB LDS ----------------
// Per thread per step: 4 gld_lds16 (2 A-chunks + 2 B-chunks). Prologue stages step0,1
// then vmcnt(4). Iter ks: stage(ks+2); compute(ks); vmcnt(4) completes (ks+1), leaves
// (ks+2) in flight (never drains in steady state); barrier. Tail: vmcnt(0)@14, none@15.

template <bool TRANS>
__global__ __launch_bounds__(256) void k_qkv(
    const ushort* __restrict__ xb, const ushort* __restrict__ WtR,
    const ushort* __restrict__ WtD, const float* __restrict__ bR,
    const float* __restrict__ bD, ushort* __restrict__ Qb,
    ushort* __restrict__ Kb, ushort* __restrict__ Vt) {
  __shared__ __align__(16) char lds[49152];   // 3 x (A 8KB + B 8KB)
  int m0 = blockIdx.x * 128;
  int n0 = (TRANS ? 1024 : 0) + blockIdx.y * 128;
  int s = m0 >> 13, bb = (m0 >> 10) & 7, lbase = m0 & 1023;
  const ushort* A = xb + (size_t)(bb * 2048 + s * 1024 + lbase) * 512;
  const ushort* Wt = (s ? WtD : WtR) + (size_t)n0 * 512;
  const float* bias = s ? bD : bR;
  int t = threadIdx.x;
  int wid = t >> 6, ln = t & 15, g = (t & 63) >> 4;
  int wr = wid >> 1, wc = wid & 1;

  // staging offsets: chunks t and t+256 of each 512-chunk (8KB) tile
  int r0 = t >> 2, c0 = t & 3;
  int r1 = (t + 256) >> 2, c1 = t & 3;
  int so0 = r0 * 512 + ((c0 ^ ((r0 >> 1) & 3)) * 8);
  int so1 = r1 * 512 + ((c1 ^ ((r1 >> 1) & 3)) * 8);
  int ldu = (t & ~63) * 16;   // wave-uniform LDS dest base (+lane*16 implicit)

  const ushort* As = A;
  const ushort* Bs = Wt;
  char* b0 = lds;
  char* b1 = lds + 16384;
  char* b2 = lds + 32768;

  f32x4 acc[4][4] = {};

  // prologue: step0 -> b0, step1 -> b1
  gld_lds16(As + so0, b0 + ldu);
  gld_lds16(As + so1, b0 + 4096 + ldu);
  gld_lds16(Bs + so0, b0 + 8192 + ldu);
  gld_lds16(Bs + so1, b0 + 12288 + ldu);
  As += 32; Bs += 32;
  gld_lds16(As + so0, b1 + ldu);
  gld_lds16(As + so1, b1 + 4096 + ldu);
  gld_lds16(Bs + so0, b1 + 8192 + ldu);
  gld_lds16(Bs + so1, b1 + 12288 + ldu);
  As += 32; Bs += 32;
  asm volatile("s_waitcnt vmcnt(4)" ::: "memory");
  __builtin_amdgcn_sched_barrier(0);
  __builtin_amdgcn_s_barrier();
  __builtin_amdgcn_sched_barrier(0);

  for (int ks = 0; ks < 16; ++ks) {
    if (ks < 14) {
      gld_lds16(As + so0, b2 + ldu);
      gld_lds16(As + so1, b2 + 4096 + ldu);
      gld_lds16(Bs + so0, b2 + 8192 + ldu);
      gld_lds16(Bs + so1, b2 + 12288 + ldu);
      As += 32; Bs += 32;
    }
    s16x8 af[4], bf[4];
    __builtin_amdgcn_s_setprio(1);
#pragma unroll
    for (int mi = 0; mi < 4; ++mi) af[mi] = lds_frag32(b0, wr * 64 + mi * 16 + ln, g);
#pragma unroll
    for (int ni = 0; ni < 4; ++ni) bf[ni] = lds_frag32(b0 + 8192, wc * 64 + ni * 16 + ln, g);
#pragma unroll
    for (int mi = 0; mi < 4; ++mi)
#pragma unroll
      for (int ni = 0; ni < 4; ++ni)
        acc[mi][ni] = TRANS ? mfma16(bf[ni], af[mi], acc[mi][ni])
                            : mfma16(af[mi], bf[ni], acc[mi][ni]);
    __builtin_amdgcn_s_setprio(0);

    if (ks < 15) {
      if (ks < 14) {
        asm volatile("s_waitcnt vmcnt(4)" ::: "memory");
      } else {
        asm volatile("s_waitcnt vmcnt(0)" ::: "memory");
      }
      __builtin_amdgcn_sched_barrier(0);
      __builtin_amdgcn_s_barrier();
      __builtin_amdgcn_sched_barrier(0);
    }
    char* tmp = b0; b0 = b1; b1 = b2; b2 = tmp;
  }

  int hb_base = (s * 8 + bb) * 8;
  if (!TRANS) {
    bool isK = (n0 >> 9) != 0;
    ushort* dst = isK ? Kb : Qb;
    float sc = isK ? 1.0f : 0.18033688011112042f;  // 0.125 * log2(e)
#pragma unroll
    for (int mi = 0; mi < 4; ++mi)
#pragma unroll
      for (int ni = 0; ni < 4; ++ni) {
        f32x4 v = acc[mi][ni];
        int col = n0 + wc * 64 + ni * 16 + ln;
        int h = (col >> 6) & 7, d = col & 63;
        float bv = bias[col];
        ushort* hp = dst + ((size_t)(hb_base + h) << 16);
        int lr = lbase + wr * 64 + mi * 16 + g * 4;
#pragma unroll
        for (int j = 0; j < 4; ++j) hp[(lr + j) * 64 + d] = f2bf((v[j] + bv) * sc);
      }
  } else {
    // epilogue via LDS: tile [128 c-rows][128 phi(l)] 16B-chunk XOR swizzled, then
    // coalesced stores. Barrier first: LDS still held compute buffers.
    __syncthreads();
    ushort* et = (ushort*)lds;
#pragma unroll
    for (int mi = 0; mi < 4; ++mi) {
      int ll = wr * 64 + mi * 16 + ln;
      int lpl = (ll & ~63) | (ll & 0x23) | ((ll & 0x0C) << 1) | ((ll & 0x10) >> 2);
      int chunk = lpl >> 3, within = lpl & 7;
#pragma unroll
      for (int ni = 0; ni < 4; ++ni) {
        f32x4 v = acc[mi][ni];
        int crb = wc * 64 + ni * 16 + g * 4;
#pragma unroll
        for (int j = 0; j < 4; ++j) {
          int cr = crb + j;
          float bv = bias[n0 + cr];
          *(ushort*)((char*)et + cr * 256 + ((chunk ^ (cr & 15)) * 16) + within * 2)
              = f2bf(v[j] + bv);
        }
      }
    }
    __syncthreads();
#pragma unroll
    for (int pass = 0; pass < 8; ++pass) {
      int rrow = pass * 16 + (t >> 4);
      int c16 = t & 15;
      int col = n0 + rrow;
      int h = (col >> 6) & 7, d = col & 63;
      uint4 vv = *(const uint4*)((const char*)et + rrow * 256 + ((c16 ^ (rrow & 15)) * 16));
      *reinterpret_cast<uint4*>(Vt + ((size_t)(hb_base + h) << 16) + d * 1024 + lbase + c16 * 8)
          = vv;
    }
  }
}

// ---------------- attention (1024 blk x 512 thr, 8 waves x 16q, 2-deep 32KB) ----------
// 4 blocks/CU (threads- and LDS-feasible), 32 waves/CU. Per thread 2 stage ops/tile.
// Iter t: issue stage(t+1); QK(t); softmax; PV(t); vmcnt(0) (own ops, issued a full
// phase earlier); s_barrier (publishes stage(t+1), protects reuse).

__global__ __launch_bounds__(512) void k_attn(const ushort* __restrict__ Qb,
                                              const ushort* __restrict__ Kb,
                                              const ushort* __restrict__ Vt,
                                              ushort* __restrict__ AO) {
  __shared__ __align__(16) char lds[32768];   // 2 x (K 8KB + V 8KB)
  int bid = blockIdx.x;
  int set = bid & 127, qb = bid >> 7;          // qb 0..7, 128 q-rows per block
  int pair = set & 1, h = (set >> 1) & 7, bb = set >> 4;
  int sQ = 1 - pair, sKV = pair;
  const ushort* Qp = Qb + ((size_t)((sQ * 8 + bb) * 8 + h) << 16);
  const ushort* Kp = Kb + ((size_t)((sKV * 8 + bb) * 8 + h) << 16);
  const ushort* Vp = Vt + ((size_t)((sKV * 8 + bb) * 8 + h) << 16);
  int t = threadIdx.x, w = t >> 6, ln = t & 15, g = (t & 63) >> 4;
  int q0 = qb * 128 + w * 16;
  s16x8 qf0 = ld16(Qp + (q0 + ln) * 64 + g * 8);
  s16x8 qf1 = ld16(Qp + (q0 + ln) * 64 + 32 + g * 8);

  int r = t >> 3, cc = t & 7;
  int kof = r * 64 + ((cc ^ (r & 7)) * 8);
  int vof = r * 1024 + ((cc ^ (r & 7)) * 8);
  int ldst = (t & ~63) * 16;

  float ls = 0.f;
  f32x4 oc[4] = {};

  const ushort* kstage = Kp;
  const ushort* vstage = Vp;

  char* bc = lds;
  char* bn = lds + 16384;

  gld_lds16(kstage + kof, bc + ldst);
  gld_lds16(vstage + vof, bc + 8192 + ldst);
  kstage += 4096; vstage += 64;
  asm volatile("s_waitcnt vmcnt(0)" ::: "memory");
  __builtin_amdgcn_sched_barrier(0);
  __builtin_amdgcn_s_barrier();
  __builtin_amdgcn_sched_barrier(0);

  for (int it = 0; it < 16; ++it) {
    if (it < 15) {
      gld_lds16(kstage + kof, bn + ldst);
      gld_lds16(vstage + vof, bn + 8192 + ldst);
      kstage += 4096; vstage += 64;
    }

    f32x4 z[4];
    __builtin_amdgcn_s_setprio(1);
#pragma unroll
    for (int s = 0; s < 4; ++s) {
      s16x8 k0 = lds_frag(bc, s * 16 + ln, g);
      s16x8 k1 = lds_frag(bc, s * 16 + ln, 4 + g);
      f32x4 z1 = {}; z1 = mfma16(k0, qf0, z1); z1 = mfma16(k1, qf1, z1); z[s] = z1;
    }
    __builtin_amdgcn_s_setprio(0);

    unsigned int pw[8];
#pragma unroll
    for (int s = 0; s < 4; ++s) {
      float p0 = exp2fast(z[s][0]), p1 = exp2fast(z[s][1]);
      float p2 = exp2fast(z[s][2]), p3 = exp2fast(z[s][3]);
      ls += (p0 + p1) + (p2 + p3);
      pw[2 * s] = pack2(p0, p1); pw[2 * s + 1] = pack2(p2, p3);
    }
    union { uint4 u; s16x8 v; } c0, c1;
    c0.u = make_uint4(pw[0], pw[1], pw[2], pw[3]);
    c1.u = make_uint4(pw[4], pw[5], pw[6], pw[7]);
    s16x8 pf0 = c0.v, pf1 = c1.v;

    __builtin_amdgcn_s_setprio(1);
#pragma unroll
    for (int d = 0; d < 4; ++d) {
      s16x8 v0 = lds_frag(bc + 8192, d * 16 + ln, g);
      s16x8 v1 = lds_frag(bc + 8192, d * 16 + ln, 4 + g);
      oc[d] = mfma16(v0, pf0, oc[d]);
      oc[d] = mfma16(v1, pf1, oc[d]);
    }
    __builtin_amdgcn_s_setprio(0);

    if (it < 15) {
      asm volatile("s_waitcnt vmcnt(0)" ::: "memory");
      __builtin_amdgcn_sched_barrier(0);
      __builtin_amdgcn_s_barrier();
      __builtin_amdgcn_sched_barrier(0);
    }
    char* tmp = bc; bc = bn; bn = tmp;
  }

  ls += __shfl_xor(ls, 16, 64);
  ls += __shfl_xor(ls, 32, 64);
  float inv = 1.0f / ls;
  int orow = bb * 2048 + pair * 1024 + q0 + ln;
#pragma unroll
  for (int d = 0; d < 4; ++d) {
    uint2 st;
    st.x = pack2(oc[d][0] * inv, oc[d][1] * inv);
    st.y = pack2(oc[d][2] * inv, oc[d][3] * inv);
    *reinterpret_cast<uint2*>(AO + (size_t)orow * 512 + h * 64 + d * 16 + 4 * g) = st;
  }
}

// ---------------- output projection GEMM (2-phase double-buffered, BK=64) -------------

__global__ __launch_bounds__(256) void k_gemm_proj(const ushort* __restrict__ AO,
                                                   const ushort* __restrict__ WtP,
                                                   const float* __restrict__ bP,
                                                   float* __restrict__ Out) {
  __shared__ __align__(16) char lds[65536];
  int m0 = blockIdx.x * 128, n0 = blockIdx.y * 128;
  const ushort* A = AO + (size_t)m0 * 512;
  const ushort* Wt = WtP + (size_t)n0 * 512;
  int t = threadIdx.x;
  int wid = t >> 6, ln = t & 15, g = (t & 63) >> 4;
  int wr = wid >> 1, wc = wid & 1;
  f32x4 acc[4][4] = {};
  stage_lds(A, 512, lds, t);
  stage_lds(Wt, 512, lds + 16384, t);
  __syncthreads();
  for (int ks = 0; ks < 8; ++ks) {
    char* cbuf = lds + (ks & 1) * 32768;
    if (ks < 7) {
      char* nbuf = lds + ((ks + 1) & 1) * 32768;
      stage_lds(A + (ks + 1) * 64, 512, nbuf, t);
      stage_lds(Wt + (ks + 1) * 64, 512, nbuf + 16384, t);
    }
    char* ldsA = cbuf;
    char* ldsB = cbuf + 16384;
#pragma unroll
    for (int kk = 0; kk < 2; ++kk) {
      s16x8 af[4], bf[4];
#pragma unroll
      for (int mi = 0; mi < 4; ++mi) af[mi] = lds_frag(ldsA, wr * 64 + mi * 16 + ln, kk * 4 + g);
#pragma unroll
      for (int ni = 0; ni < 4; ++ni) bf[ni] = lds_frag(ldsB, wc * 64 + ni * 16 + ln, kk * 4 + g);
#pragma unroll
      for (int mi = 0; mi < 4; ++mi)
#pragma unroll
        for (int ni = 0; ni < 4; ++ni) acc[mi][ni] = mfma16(af[mi], bf[ni], acc[mi][ni]);
    }
    __syncthreads();
  }
#pragma unroll
  for (int mi = 0; mi < 4; ++mi)
#pragma unroll
    for (int ni = 0; ni < 4; ++ni) {
      f32x4 v = acc[mi][ni];
      int col = n0 + wc * 64 + ni * 16 + ln;
      float bv = bP[col];
      int r0 = m0 + wr * 64 + mi * 16 + g * 4;
#pragma unroll
      for (int j = 0; j < 4; ++j) Out[(size_t)(r0 + j) * 512 + col] = v[j] + bv;
    }
}

// ---------------- launch ----------------

extern "C" void kernel_launch(void* const* d_in, const int* in_sizes, int n_in,
                              void* d_out, int out_size, void* d_ws, size_t ws_size,
                              hipStream_t stream) {
  const float* x      = (const float*)d_in[0];
  const float* W_rgb  = (const float*)d_in[1];
  const float* b_rgb  = (const float*)d_in[2];
  const float* W_dep  = (const float*)d_in[3];
  const float* b_dep  = (const float*)d_in[4];
  const float* W_proj = (const float*)d_in[5];
  const float* b_proj = (const float*)d_in[6];
  float* out = (float*)d_out;

  char* ws = (char*)d_ws;
  ushort* xb  = (ushort*)(ws + 0);
  ushort* WtR = (ushort*)(ws + 16777216);
  ushort* WtD = (ushort*)(ws + 18350080);
  ushort* WtP = (ushort*)(ws + 19922944);
  ushort* Qb  = (ushort*)(ws + 20447232);
  ushort* Kb  = (ushort*)(ws + 37224448);
  ushort* Vt  = (ushort*)(ws + 54001664);
  ushort* AO  = (ushort*)(ws + 70778880);

  k_prep<<<9984, 256, 0, stream>>>(x, xb, W_rgb, WtR, W_dep, WtD, W_proj, WtP);
  k_qkv<false><<<dim3(128, 8), 256, 0, stream>>>(xb, WtR, WtD, b_rgb, b_dep, Qb, Kb, Vt);
  k_qkv<true><<<dim3(128, 4), 256, 0, stream>>>(xb, WtR, WtD, b_rgb, b_dep, Qb, Kb, Vt);
  k_attn<<<1024, 512, 0, stream>>>(Qb, Kb, Vt, AO);
  k_gemm_proj<<<dim3(128, 4), 256, 0, stream>>>(AO, WtP, b_proj, out);
}